// Round 2
// baseline (476.158 us; speedup 1.0000x reference)
//
#include <hip/hip_runtime.h>
#include <hip/hip_bf16.h>
#include <math.h>

#define B_ 32
#define C_ 2048
#define HW_ 576          // 24*24
#define P_ 4
#define HID_ 128         // C/RED
#define NCHUNK_ 8        // c-chunks of 256 channels
#define NSLOT_ 32        // NCHUNK_ * 4 groups

// ---------------- pool: pooled[b,c] = mean_hw x[b,c,hw] ----------------
// one wave per (b,c) row of 576 floats (144 float4), 4 waves/block
__global__ void pool_kernel(const float* __restrict__ x, float* __restrict__ pooled) {
    int gwave = blockIdx.x * 4 + (threadIdx.x >> 6);   // [0, 65536)
    int lane  = threadIdx.x & 63;
    const float4* xp4 = (const float4*)(x + (size_t)gwave * HW_);
    float s = 0.f;
    for (int i = lane; i < HW_ / 4; i += 64) {         // 144 float4
        float4 v = xp4[i];
        s += v.x + v.y + v.z + v.w;
    }
    #pragma unroll
    for (int off = 32; off > 0; off >>= 1) s += __shfl_down(s, off, 64);
    if (lane == 0) pooled[gwave] = s * (1.0f / (float)HW_);
}

// ---------------- fc1: hidden[b,j] = silu(pooled[b,:]·fc1_w[j,:] + b1[j]) ----------------
// one wave per output (32*128 = 4096 outputs), 4 waves/block -> 1024 blocks
__global__ void fc1_kernel(const float* __restrict__ pooled, const float* __restrict__ w,
                           const float* __restrict__ bias, float* __restrict__ hidden) {
    int o    = blockIdx.x * 4 + (threadIdx.x >> 6);    // [0, 4096)
    int lane = threadIdx.x & 63;
    int b = o >> 7;        // /128
    int j = o & 127;
    const float* pr = pooled + (size_t)b * C_;
    const float* wr = w + (size_t)j * C_;
    float s = 0.f;
    for (int k = lane; k < C_; k += 64) s += pr[k] * wr[k];
    #pragma unroll
    for (int off = 32; off > 0; off >>= 1) s += __shfl_down(s, off, 64);
    if (lane == 0) {
        float z = s + bias[j];
        hidden[o] = z / (1.0f + expf(-z));             // silu
    }
}

// ---------------- fc2: dw[b,o] = hidden[b,:]·fc2_w[o,:] + b2[o] ----------------
// grid 256 blocks (b=32 x jc=8), 4 waves/block, each wave loops 256 outputs
__global__ void fc2_kernel(const float* __restrict__ hidden, const float* __restrict__ w,
                           const float* __restrict__ bias, float* __restrict__ dw) {
    int b  = blockIdx.x >> 3;
    int jc = blockIdx.x & 7;
    int tid = threadIdx.x;
    int wave = tid >> 6, lane = tid & 63;

    __shared__ float h[HID_];
    if (tid < HID_) h[tid] = hidden[(size_t)b * HID_ + tid];
    __syncthreads();
    float h0 = h[lane], h1 = h[lane + 64];

    int jbase = jc * 1024 + wave * 256;
    for (int i = 0; i < 256; ++i) {
        int j = jbase + i;
        const float* wr = w + (size_t)j * HID_;
        float s = h0 * wr[lane] + h1 * wr[lane + 64];
        #pragma unroll
        for (int off = 32; off > 0; off >>= 1) s += __shfl_down(s, off, 64);
        if (lane == 0) dw[(size_t)b * (P_ * C_) + j] = s + bias[j];
    }
}

// ---------------- bias_const[b,p] = sum_c conv_b[c]*dw[b,p,c] ----------------
// one wave per (b,p) (128 outputs), 4 waves/block -> 32 blocks
__global__ void biasc_kernel(const float* __restrict__ conv_b, const float* __restrict__ dw,
                             float* __restrict__ bias_const) {
    int o    = blockIdx.x * 4 + (threadIdx.x >> 6);    // [0, 128) == b*4+p
    int lane = threadIdx.x & 63;
    const float* dr = dw + (size_t)o * C_;
    float s = 0.f;
    for (int k = lane; k < C_; k += 64) s += conv_b[k] * dr[k];
    #pragma unroll
    for (int off = 32; off > 0; off >>= 1) s += __shfl_down(s, off, 64);
    if (lane == 0) bias_const[o] = s;
}

// ---------------- einsum partials ----------------
// grid (b=32, chunk=8); 256 channels per chunk; 576 threads.
// threads split into 4 groups of 144; group g owns channels c0+g+4k and
// float4 hw-segment [4i, 4i+4). Writes part[b][slot=chunk*4+g][p][hw].
__global__ void einsum_kernel(const float* __restrict__ x, const float* __restrict__ conv_w,
                              const float* __restrict__ dw, float* __restrict__ part) {
    int b     = blockIdx.x;
    int chunk = blockIdx.y;
    int c0    = chunk * 256;
    int tid   = threadIdx.x;                           // [0, 576)

    __shared__ float4 m4[256];                         // m4[c] = {cw*dw[p=0..3]}
    if (tid < 256) {
        float cw = conv_w[c0 + tid];
        const float* dr = dw + (size_t)b * (P_ * C_) + c0 + tid;
        float4 v;
        v.x = cw * dr[0 * C_];
        v.y = cw * dr[1 * C_];
        v.z = cw * dr[2 * C_];
        v.w = cw * dr[3 * C_];
        m4[tid] = v;
    }
    __syncthreads();

    int g = tid / 144;                                 // 0..3
    int i = tid - g * 144;                             // 0..143  (float4 index in hw)

    float4 a0 = {0,0,0,0}, a1 = {0,0,0,0}, a2 = {0,0,0,0}, a3 = {0,0,0,0};
    const float* xb = x + ((size_t)b * C_ + c0) * HW_;
    #pragma unroll 4
    for (int k = 0; k < 64; ++k) {
        int c = g + 4 * k;
        float4 v = ((const float4*)(xb + (size_t)c * HW_))[i];
        float4 m = m4[c];
        a0.x += v.x * m.x; a0.y += v.y * m.x; a0.z += v.z * m.x; a0.w += v.w * m.x;
        a1.x += v.x * m.y; a1.y += v.y * m.y; a1.z += v.z * m.y; a1.w += v.w * m.y;
        a2.x += v.x * m.z; a2.y += v.y * m.z; a2.z += v.z * m.z; a2.w += v.w * m.z;
        a3.x += v.x * m.w; a3.y += v.y * m.w; a3.z += v.z * m.w; a3.w += v.w * m.w;
    }
    int slot = chunk * 4 + g;
    float4* pp = (float4*)(part + (((size_t)b * NSLOT_ + slot) * P_) * HW_) + i;
    pp[0 * (HW_ / 4)] = a0;
    pp[1 * (HW_ / 4)] = a1;
    pp[2 * (HW_ / 4)] = a2;
    pp[3 * (HW_ / 4)] = a3;
}

// ---------------- reduce slots + bias + softmax over p ----------------
// thread per (b,hw): 18432 threads = 72 blocks * 256
__global__ void softmax_kernel(const float* __restrict__ part, const float* __restrict__ bias_const,
                               float* __restrict__ out) {
    int idx = blockIdx.x * 256 + threadIdx.x;          // [0, 18432)
    int b  = idx / HW_;
    int hw = idx - b * HW_;
    const float* bc = bias_const + b * P_;
    float v0 = bc[0], v1 = bc[1], v2 = bc[2], v3 = bc[3];
    const float* pb = part + ((size_t)b * NSLOT_ * P_) * HW_ + hw;
    #pragma unroll 8
    for (int s = 0; s < NSLOT_; ++s) {
        const float* ps = pb + (size_t)s * P_ * HW_;
        v0 += ps[0 * HW_];
        v1 += ps[1 * HW_];
        v2 += ps[2 * HW_];
        v3 += ps[3 * HW_];
    }
    float mx = fmaxf(fmaxf(v0, v1), fmaxf(v2, v3));
    float e0 = expf(v0 - mx), e1 = expf(v1 - mx), e2 = expf(v2 - mx), e3 = expf(v3 - mx);
    float inv = 1.0f / (e0 + e1 + e2 + e3);
    float* op = out + ((size_t)b * P_) * HW_ + hw;
    op[0 * HW_] = e0 * inv;
    op[1 * HW_] = e1 * inv;
    op[2 * HW_] = e2 * inv;
    op[3 * HW_] = e3 * inv;
}

extern "C" void kernel_launch(void* const* d_in, const int* in_sizes, int n_in,
                              void* d_out, int out_size, void* d_ws, size_t ws_size,
                              hipStream_t stream) {
    const float* x      = (const float*)d_in[0];
    const float* fc1_w  = (const float*)d_in[1];
    const float* fc1_b  = (const float*)d_in[2];
    const float* fc2_w  = (const float*)d_in[3];
    const float* fc2_b  = (const float*)d_in[4];
    const float* conv_w = (const float*)d_in[5];
    const float* conv_b = (const float*)d_in[6];
    float* out = (float*)d_out;

    // workspace layout (floats)
    float* ws      = (float*)d_ws;
    float* pooled  = ws;                    // 32*2048        = 65536
    float* hidden  = pooled + 65536;        // 32*128         = 4096
    float* dw      = hidden + 4096;         // 32*8192        = 262144
    float* bias_c  = dw + 262144;           // 128
    float* part    = bias_c + 128;          // 32*32*4*576    = 2359296 (9.4 MB)

    pool_kernel<<<16384, 256, 0, stream>>>(x, pooled);
    fc1_kernel<<<1024, 256, 0, stream>>>(pooled, fc1_w, fc1_b, hidden);
    fc2_kernel<<<256, 256, 0, stream>>>(hidden, fc2_w, fc2_b, dw);
    biasc_kernel<<<32, 256, 0, stream>>>(conv_b, dw, bias_c);
    einsum_kernel<<<dim3(B_, NCHUNK_), 576, 0, stream>>>(x, conv_w, dw, part);
    softmax_kernel<<<72, 256, 0, stream>>>(part, bias_c, out);
}

// Round 3
// 283.780 us; speedup vs baseline: 1.6779x; 1.6779x over previous
//
#include <hip/hip_runtime.h>
#include <hip/hip_bf16.h>
#include <math.h>

#define B_ 32
#define C_ 2048
#define HW_ 576          // 24*24
#define P_ 4
#define HID_ 128         // C/RED
#define J_ 8192          // C*P
#define NCHUNK_ 8        // c-chunks of 256 channels
#define NSLOT_ 32        // NCHUNK_ * 4 groups

// ---------------- pool: pooled[b,c] = mean_hw x[b,c,hw] ----------------
// one wave per (b,c) row of 576 floats (144 float4), 4 waves/block
__global__ void pool_kernel(const float* __restrict__ x, float* __restrict__ pooled) {
    int gwave = blockIdx.x * 4 + (threadIdx.x >> 6);   // [0, 65536)
    int lane  = threadIdx.x & 63;
    const float4* xp4 = (const float4*)(x + (size_t)gwave * HW_);
    float s = 0.f;
    for (int i = lane; i < HW_ / 4; i += 64) {         // 144 float4
        float4 v = xp4[i];
        s += v.x + v.y + v.z + v.w;
    }
    #pragma unroll
    for (int off = 32; off > 0; off >>= 1) s += __shfl_down(s, off, 64);
    if (lane == 0) pooled[gwave] = s * (1.0f / (float)HW_);
}

// ---------------- fc1: hidden[b,j] = silu(pooled[b,:]·fc1_w[j,:] + b1[j]) ----------------
// one wave per output (32*128 = 4096 outputs), 4 waves/block -> 1024 blocks
__global__ void fc1_kernel(const float* __restrict__ pooled, const float* __restrict__ w,
                           const float* __restrict__ bias, float* __restrict__ hidden) {
    int o    = blockIdx.x * 4 + (threadIdx.x >> 6);    // [0, 4096)
    int lane = threadIdx.x & 63;
    int b = o >> 7;        // /128
    int j = o & 127;
    const float* pr = pooled + (size_t)b * C_;
    const float* wr = w + (size_t)j * C_;
    float s = 0.f;
    for (int k = lane; k < C_; k += 64) s += pr[k] * wr[k];
    #pragma unroll
    for (int off = 32; off > 0; off >>= 1) s += __shfl_down(s, off, 64);
    if (lane == 0) {
        float z = s + bias[j];
        hidden[o] = z / (1.0f + expf(-z));             // silu
    }
}

// ---------------- transpose fc2_w: w[j,k] (8192x128) -> wt[k,j] (128x8192) ----------------
// 32x32 LDS tiles, block (32,8), grid (128/32=4, 8192/32=256)
__global__ void transpose_w(const float* __restrict__ w, float* __restrict__ wt) {
    __shared__ float tile[32][33];
    int kt = blockIdx.x;
    int jt = blockIdx.y;
    int tx = threadIdx.x;      // 0..31
    int ty = threadIdx.y;      // 0..7
    #pragma unroll
    for (int i = 0; i < 32; i += 8)
        tile[ty + i][tx] = w[(size_t)(jt * 32 + ty + i) * HID_ + kt * 32 + tx];
    __syncthreads();
    #pragma unroll
    for (int i = 0; i < 32; i += 8)
        wt[(size_t)(kt * 32 + ty + i) * J_ + jt * 32 + tx] = tile[tx][ty + i];
}

// ---------------- fc2: dw[b,j] = hidden[b,:]·w[j,:] + b2[j], via wt[k,j] ----------------
// grid (b=32 x jc=8) = 256 blocks, 256 threads; thread owns 4 consecutive j's.
// wt loads are float4-coalesced; hidden broadcast from LDS; no shuffles.
__global__ void fc2_kernel(const float* __restrict__ hidden, const float* __restrict__ wt,
                           const float* __restrict__ bias, float* __restrict__ dw) {
    int b  = blockIdx.x >> 3;
    int jc = blockIdx.x & 7;
    int tid = threadIdx.x;

    __shared__ float h[HID_];
    if (tid < HID_) h[tid] = hidden[(size_t)b * HID_ + tid];
    __syncthreads();

    int j4 = jc * 256 + tid;                 // float4 column index: j = 4*j4
    const float4* wt4 = (const float4*)wt;   // [k][J_/4]
    float4 acc = {0.f, 0.f, 0.f, 0.f};
    #pragma unroll 8
    for (int k = 0; k < HID_; ++k) {
        float4 wv = wt4[(size_t)k * (J_ / 4) + j4];
        float hk = h[k];
        acc.x += wv.x * hk;
        acc.y += wv.y * hk;
        acc.z += wv.z * hk;
        acc.w += wv.w * hk;
    }
    const float4* b4 = (const float4*)bias;
    float4 bb = b4[j4];
    acc.x += bb.x; acc.y += bb.y; acc.z += bb.z; acc.w += bb.w;
    ((float4*)(dw + (size_t)b * J_))[j4] = acc;
}

// ---------------- bias_const[b,p] = sum_c conv_b[c]*dw[b,p,c] ----------------
// one wave per (b,p) (128 outputs), 4 waves/block -> 32 blocks
__global__ void biasc_kernel(const float* __restrict__ conv_b, const float* __restrict__ dw,
                             float* __restrict__ bias_const) {
    int o    = blockIdx.x * 4 + (threadIdx.x >> 6);    // [0, 128) == b*4+p
    int lane = threadIdx.x & 63;
    const float* dr = dw + (size_t)o * C_;
    float s = 0.f;
    for (int k = lane; k < C_; k += 64) s += conv_b[k] * dr[k];
    #pragma unroll
    for (int off = 32; off > 0; off >>= 1) s += __shfl_down(s, off, 64);
    if (lane == 0) bias_const[o] = s;
}

// ---------------- einsum partials ----------------
// grid (b=32, chunk=8); 256 channels per chunk; 576 threads.
// threads split into 4 groups of 144; group g owns channels c0+g+4k and
// float4 hw-segment [4i, 4i+4). Writes part[b][slot=chunk*4+g][p][hw].
__global__ void einsum_kernel(const float* __restrict__ x, const float* __restrict__ conv_w,
                              const float* __restrict__ dw, float* __restrict__ part) {
    int b     = blockIdx.x;
    int chunk = blockIdx.y;
    int c0    = chunk * 256;
    int tid   = threadIdx.x;                           // [0, 576)

    __shared__ float4 m4[256];                         // m4[c] = {cw*dw[p=0..3]}
    if (tid < 256) {
        float cw = conv_w[c0 + tid];
        const float* dr = dw + (size_t)b * (P_ * C_) + c0 + tid;
        float4 v;
        v.x = cw * dr[0 * C_];
        v.y = cw * dr[1 * C_];
        v.z = cw * dr[2 * C_];
        v.w = cw * dr[3 * C_];
        m4[tid] = v;
    }
    __syncthreads();

    int g = tid / 144;                                 // 0..3
    int i = tid - g * 144;                             // 0..143  (float4 index in hw)

    float4 a0 = {0,0,0,0}, a1 = {0,0,0,0}, a2 = {0,0,0,0}, a3 = {0,0,0,0};
    const float* xb = x + ((size_t)b * C_ + c0) * HW_;
    #pragma unroll 4
    for (int k = 0; k < 64; ++k) {
        int c = g + 4 * k;
        float4 v = ((const float4*)(xb + (size_t)c * HW_))[i];
        float4 m = m4[c];
        a0.x += v.x * m.x; a0.y += v.y * m.x; a0.z += v.z * m.x; a0.w += v.w * m.x;
        a1.x += v.x * m.y; a1.y += v.y * m.y; a1.z += v.z * m.y; a1.w += v.w * m.y;
        a2.x += v.x * m.z; a2.y += v.y * m.z; a2.z += v.z * m.z; a2.w += v.w * m.z;
        a3.x += v.x * m.w; a3.y += v.y * m.w; a3.z += v.z * m.w; a3.w += v.w * m.w;
    }
    int slot = chunk * 4 + g;
    float4* pp = (float4*)(part + (((size_t)b * NSLOT_ + slot) * P_) * HW_) + i;
    pp[0 * (HW_ / 4)] = a0;
    pp[1 * (HW_ / 4)] = a1;
    pp[2 * (HW_ / 4)] = a2;
    pp[3 * (HW_ / 4)] = a3;
}

// ---------------- reduce slots + bias + softmax over p ----------------
// thread per (b,hw): 18432 threads = 72 blocks * 256
__global__ void softmax_kernel(const float* __restrict__ part, const float* __restrict__ bias_const,
                               float* __restrict__ out) {
    int idx = blockIdx.x * 256 + threadIdx.x;          // [0, 18432)
    int b  = idx / HW_;
    int hw = idx - b * HW_;
    const float* bc = bias_const + b * P_;
    float v0 = bc[0], v1 = bc[1], v2 = bc[2], v3 = bc[3];
    const float* pb = part + ((size_t)b * NSLOT_ * P_) * HW_ + hw;
    #pragma unroll 8
    for (int s = 0; s < NSLOT_; ++s) {
        const float* ps = pb + (size_t)s * P_ * HW_;
        v0 += ps[0 * HW_];
        v1 += ps[1 * HW_];
        v2 += ps[2 * HW_];
        v3 += ps[3 * HW_];
    }
    float mx = fmaxf(fmaxf(v0, v1), fmaxf(v2, v3));
    float e0 = expf(v0 - mx), e1 = expf(v1 - mx), e2 = expf(v2 - mx), e3 = expf(v3 - mx);
    float inv = 1.0f / (e0 + e1 + e2 + e3);
    float* op = out + ((size_t)b * P_) * HW_ + hw;
    op[0 * HW_] = e0 * inv;
    op[1 * HW_] = e1 * inv;
    op[2 * HW_] = e2 * inv;
    op[3 * HW_] = e3 * inv;
}

extern "C" void kernel_launch(void* const* d_in, const int* in_sizes, int n_in,
                              void* d_out, int out_size, void* d_ws, size_t ws_size,
                              hipStream_t stream) {
    const float* x      = (const float*)d_in[0];
    const float* fc1_w  = (const float*)d_in[1];
    const float* fc1_b  = (const float*)d_in[2];
    const float* fc2_w  = (const float*)d_in[3];
    const float* fc2_b  = (const float*)d_in[4];
    const float* conv_w = (const float*)d_in[5];
    const float* conv_b = (const float*)d_in[6];
    float* out = (float*)d_out;

    // workspace layout (floats)
    float* ws      = (float*)d_ws;
    float* pooled  = ws;                    // 32*2048        = 65536
    float* hidden  = pooled + 65536;        // 32*128         = 4096
    float* dw      = hidden + 4096;         // 32*8192        = 262144
    float* bias_c  = dw + 262144;           // 128
    float* part    = bias_c + 128;          // 32*32*4*576    = 2359296 (9.4 MB)
    float* wt      = part + 2359296;        // 128*8192       = 1048576 (4 MB)

    pool_kernel<<<16384, 256, 0, stream>>>(x, pooled);
    fc1_kernel<<<1024, 256, 0, stream>>>(pooled, fc1_w, fc1_b, hidden);
    transpose_w<<<dim3(4, 256), dim3(32, 8), 0, stream>>>(fc2_w, wt);
    fc2_kernel<<<256, 256, 0, stream>>>(hidden, wt, fc2_b, dw);
    biasc_kernel<<<32, 256, 0, stream>>>(conv_b, dw, bias_c);
    einsum_kernel<<<dim3(B_, NCHUNK_), 576, 0, stream>>>(x, conv_w, dw, part);
    softmax_kernel<<<72, 256, 0, stream>>>(part, bias_c, out);
}